// Round 19
// baseline (349.989 us; speedup 1.0000x reference)
//
#include <hip/hip_runtime.h>

// Problem constants
#define B_ 32
#define N_ 4096
#define C_ 768
#define H_ 8
#define DH_ 96
#define TILE 8
#define ROWS 256
#define NT (ROWS / TILE)     // 32 tiles per chunk
#define NCH (N_ / ROWS)      // 16 chunks per batch row
#define TFL (TILE * C_)      // floats per tile buffer (6144)
#define NDG 4                // d-groups in prep

struct F3 { float x, y, z; };

#define BARL() do { asm volatile("s_waitcnt lgkmcnt(0)" ::: "memory"); \
                    __builtin_amdgcn_s_barrier(); } while (0)

// ---- prep: grid (H, NDG) = 32 blocks (R17-validated) ----------------------
__global__ __launch_bounds__(256) void k_prep(const float* __restrict__ queries,
    const float* __restrict__ Wq, const float* __restrict__ Wkv,
    float* __restrict__ wqep) {
  __shared__ float qh[24];
  const int h = blockIdx.x, dg = blockIdx.y;
  const int tid = threadIdx.x, lane = tid & 63, wv = tid >> 6;
  const int d0 = dg * 24;

  float4 q0 = *(const float4*)(queries + lane * 4);
  float4 q1 = *(const float4*)(queries + 256 + lane * 4);
  float4 q2 = *(const float4*)(queries + 512 + lane * 4);
#pragma unroll
  for (int j = 0; j < 6; ++j) {
    int dl = wv * 6 + j;
    const float* wr = Wq + (size_t)(h * DH_ + d0 + dl) * C_ + lane * 4;
    float4 w0 = *(const float4*)(wr);
    float4 w1 = *(const float4*)(wr + 256);
    float4 w2 = *(const float4*)(wr + 512);
    float a = w0.x * q0.x;
    a = fmaf(w0.y, q0.y, a); a = fmaf(w0.z, q0.z, a); a = fmaf(w0.w, q0.w, a);
    a = fmaf(w1.x, q1.x, a); a = fmaf(w1.y, q1.y, a);
    a = fmaf(w1.z, q1.z, a); a = fmaf(w1.w, q1.w, a);
    a = fmaf(w2.x, q2.x, a); a = fmaf(w2.y, q2.y, a);
    a = fmaf(w2.z, q2.z, a); a = fmaf(w2.w, q2.w, a);
#pragma unroll
    for (int off = 32; off; off >>= 1) a += __shfl_xor(a, off);
    if (lane == 0) qh[dl] = a;
  }
  __syncthreads();

  const int c0 = tid * 3;
  const float* base = Wkv + (size_t)(h * DH_ + d0) * C_ + c0;
  float a0 = 0.f, a1 = 0.f, a2 = 0.f;
#pragma unroll 8
  for (int d = 0; d < 24; ++d) {
    float qd = qh[d];
    const float* p = base + (size_t)d * C_;
    a0 = fmaf(qd, p[0], a0);
    a1 = fmaf(qd, p[1], a1);
    a2 = fmaf(qd, p[2], a2);
  }
  float* o = wqep + ((size_t)dg * H_ + h) * C_ + c0;
  o[0] = a0; o[1] = a1; o[2] = a2;
}

// ---- single-pass fused: 512-thread blocks, 4 waves/SIMD -------------------
// grid (NCH, B_) = 512 blocks x 512 threads -> 2 blocks/CU, 16 waves/CU.
// R16's pipelined schedule: BARL -> STAGE(t+1) -> C(t-1) -> vmcnt(3) -> A(t).
// Phase A: wave w = rows {(w&3)*2,+1} x heads (w>>2)*4..+3 (wq 48 VGPR).
// Phase C: thread (of 512) = 3 cols x 4 heads (acc 12 VGPR). ~80 VGPR total.
__global__ __launch_bounds__(512, 4) void k_fused(
    const float* __restrict__ x, const float* __restrict__ wqep,
    float* __restrict__ part, float* __restrict__ sout) {
  extern __shared__ __align__(16) float xdyn[];       // 3 * TFL (73.7 KB)
  __shared__ __align__(16) float wlds[2][TILE][H_];   // parity-split weights
  __shared__ float sden[8][4];

  const int ch = blockIdx.x, b = blockIdx.y;
  const int tid = threadIdx.x, lane = tid & 63, wid = tid >> 6;   // wid 0..7
  const int rbase = (wid & 3) * 2;        // phase A rows
  const int hbase = (wid >> 2) * 4;       // phase A head group
  const int col = lane * 4;
  const int chh = tid >> 8;               // phase C head-half (0/1)
  const int cc0 = (tid & 255) * 3;        // phase C col slice
  const float* xc = x + ((size_t)b * N_ + (size_t)ch * ROWS) * C_;

  // wq for this wave's 4 heads: sum the NDG prep partials (one-time)
  float4 wqv[4][3];
#pragma unroll
  for (int h = 0; h < 4; ++h)
#pragma unroll
    for (int p = 0; p < 3; ++p) {
      float4 s = *(const float4*)(wqep + (size_t)(hbase + h) * C_ + p * 256 + col);
#pragma unroll
      for (int dg = 1; dg < NDG; ++dg) {
        float4 v = *(const float4*)(wqep + ((size_t)dg * H_ + hbase + h) * C_ + p * 256 + col);
        s.x += v.x; s.y += v.y; s.z += v.z; s.w += v.w;
      }
      wqv[h][p] = s;
    }

  float acc[4][3];   // this thread's 4 heads (chh*4..+3) x 3 cols
#pragma unroll
  for (int h = 0; h < 4; ++h) { acc[h][0] = 0.f; acc[h][1] = 0.f; acc[h][2] = 0.f; }
  float sreg = 0.f;

#define STAGE(BI, T) do {                                                      \
    const float* gt_ = xc + (size_t)(T) * TFL;                                 \
    float* bn_ = xdyn + (size_t)(BI) * TFL;                                    \
    _Pragma("unroll")                                                          \
    for (int j = 0; j < 3; ++j) {                                              \
      int k = wid * 3 + j;                                                     \
      __builtin_amdgcn_global_load_lds(                                        \
        (const __attribute__((address_space(1))) void*)(gt_ + k * 256 + lane * 4), \
        (__attribute__((address_space(3))) void*)(bn_ + k * 256),              \
        16, 0, 0);                                                             \
    }                                                                          \
  } while (0)

#define PHASEC(XB, PC) do {                                                    \
    const float* wp_ = &wlds[PC][0][chh * 4];                                  \
    _Pragma("unroll")                                                          \
    for (int r = 0; r < TILE; ++r) {                                           \
      float4 wv = *(const float4*)(wp_ + r * H_);   /* wave-uniform bcast */   \
      F3 xv = *(const F3*)((XB) + (size_t)r * C_ + cc0);                       \
      acc[0][0] = fmaf(wv.x, xv.x, acc[0][0]);                                 \
      acc[0][1] = fmaf(wv.x, xv.y, acc[0][1]);                                 \
      acc[0][2] = fmaf(wv.x, xv.z, acc[0][2]);                                 \
      acc[1][0] = fmaf(wv.y, xv.x, acc[1][0]);                                 \
      acc[1][1] = fmaf(wv.y, xv.y, acc[1][1]);                                 \
      acc[1][2] = fmaf(wv.y, xv.z, acc[1][2]);                                 \
      acc[2][0] = fmaf(wv.z, xv.x, acc[2][0]);                                 \
      acc[2][1] = fmaf(wv.z, xv.y, acc[2][1]);                                 \
      acc[2][2] = fmaf(wv.z, xv.z, acc[2][2]);                                 \
      acc[3][0] = fmaf(wv.w, xv.x, acc[3][0]);                                 \
      acc[3][1] = fmaf(wv.w, xv.y, acc[3][1]);                                 \
      acc[3][2] = fmaf(wv.w, xv.z, acc[3][2]);                                 \
    }                                                                          \
  } while (0)

  STAGE(0, 0);   // prologue: tile 0

  int bi = 0;    // buffer of tile t
  for (int t = 0; t < NT; ++t) {
    BARL();   // wlds(t-1) visible; C(t-2) done -> buffer (bi+1)%3 free
    if (t + 1 < NT) { int nb = bi + 1; if (nb >= 3) nb -= 3; STAGE(nb, t + 1); }

    // ---- Phase C(t-1): previous tile (data long resident) ------------------
    if (t > 0) {
      int pb = bi + 2; if (pb >= 3) pb -= 3;
      PHASEC(xdyn + (size_t)pb * TFL, (t & 1) ^ 1);
    }

    // ---- wait for tile t's own 3 loads (t+1's 3 may stay outstanding) ------
    if (t + 1 < NT) { asm volatile("s_waitcnt vmcnt(3)" ::: "memory"); }
    else            { asm volatile("s_waitcnt vmcnt(0)" ::: "memory"); }

    const float* xb = xdyn + (size_t)bi * TFL;
    const int P = t & 1;

    // ---- Phase A(t): 2 rows x 4 heads -> wlds[P] ---------------------------
#pragma unroll
    for (int rr = 0; rr < 2; ++rr) {
      const int r = rbase + rr;
      const float* xr = xb + r * C_ + col;
      float4 xv0 = *(const float4*)(xr);
      float4 xv1 = *(const float4*)(xr + 256);
      float4 xv2 = *(const float4*)(xr + 512);
      float d[4];
#pragma unroll
      for (int h = 0; h < 4; ++h) {
        float a = xv0.x * wqv[h][0].x;
        a = fmaf(xv0.y, wqv[h][0].y, a);
        a = fmaf(xv0.z, wqv[h][0].z, a);
        a = fmaf(xv0.w, wqv[h][0].w, a);
        a = fmaf(xv1.x, wqv[h][1].x, a);
        a = fmaf(xv1.y, wqv[h][1].y, a);
        a = fmaf(xv1.z, wqv[h][1].z, a);
        a = fmaf(xv1.w, wqv[h][1].w, a);
        a = fmaf(xv2.x, wqv[h][2].x, a);
        a = fmaf(xv2.y, wqv[h][2].y, a);
        a = fmaf(xv2.z, wqv[h][2].z, a);
        a = fmaf(xv2.w, wqv[h][2].w, a);
        d[h] = a;
      }
      const int s1 = lane & 1, s2 = lane & 2;
      float A0 = (s1 ? d[1] : d[0]) + __shfl_xor(s1 ? d[0] : d[1], 1);
      float A1 = (s1 ? d[3] : d[2]) + __shfl_xor(s1 ? d[2] : d[3], 1);
      float Q  = (s2 ? A1 : A0) + __shfl_xor(s2 ? A0 : A1, 2);
      Q += __shfl_xor(Q, 4);
      Q += __shfl_xor(Q, 8);
      Q += __shfl_xor(Q, 16);
      Q += __shfl_xor(Q, 32);
      float w = __expf(Q - 20.f);
      if (lane < 4) { wlds[P][r][hbase + lane] = w; sreg += w; }
    }
    ++bi; if (bi >= 3) bi -= 3;
  }

  // final: C(NT-1) — wlds[(NT-1)&1] needs a barrier for visibility
  BARL();
  {
    int pb = bi + 2; if (pb >= 3) pb -= 3;
    PHASEC(xdyn + (size_t)pb * TFL, (NT - 1) & 1);
  }

  // ---- epilogue: chunk partials + denominators ------------------------------
  {
    float* pp = part + ((size_t)(b * NCH + ch) * H_ + chh * 4) * C_ + cc0;
#pragma unroll
    for (int h = 0; h < 4; ++h) {
      F3 o = { acc[h][0], acc[h][1], acc[h][2] };
      *(F3*)(pp + (size_t)h * C_) = o;
    }
    if (lane < 4) sden[wid][lane] = sreg;
    BARL();
    if (tid < H_) {
      int g = (tid >> 2) * 4;   // wave group for this head
      float den = sden[g][tid & 3] + sden[g + 1][tid & 3]
                + sden[g + 2][tid & 3] + sden[g + 3][tid & 3];
      sout[(size_t)(b * NCH + ch) * H_ + tid] = den;
    }
  }
#undef PHASEC
#undef STAGE
}

// ---- combout (validated R12) ----------------------------------------------
__global__ __launch_bounds__(256) void k_combout(
    const float* __restrict__ part, const float* __restrict__ spart,
    const float* __restrict__ Wkv, float* __restrict__ out1) {
  __shared__ __align__(16) float xb[C_];
  const int h = blockIdx.x, b = blockIdx.y;
  const int tid = threadIdx.x, lane = tid & 63, wv = tid >> 6;

  const float* sp = spart + (size_t)b * NCH * H_ + h;
  float den = 0.f;
#pragma unroll
  for (int ch = 0; ch < NCH; ++ch) den += sp[(size_t)ch * H_];
  const float inv = 1.f / den;

  const int c0 = tid * 3;
  const float* pp = part + ((size_t)(b * NCH) * H_ + h) * C_ + c0;
  float a0 = 0.f, a1 = 0.f, a2 = 0.f;
#pragma unroll
  for (int ch = 0; ch < NCH; ++ch) {
    const float* p = pp + (size_t)ch * H_ * C_;
    a0 += p[0]; a1 += p[1]; a2 += p[2];
  }
  xb[c0] = a0 * inv; xb[c0 + 1] = a1 * inv; xb[c0 + 2] = a2 * inv;
  __syncthreads();

  float4 x0 = *(const float4*)(&xb[lane * 4]);
  float4 x1 = *(const float4*)(&xb[256 + lane * 4]);
  float4 x2 = *(const float4*)(&xb[512 + lane * 4]);
#pragma unroll 4
  for (int j = 0; j < 24; ++j) {
    int e = h * DH_ + wv * 24 + j;
    const float* wr = Wkv + (size_t)(C_ + e) * C_ + lane * 4;
    float4 w0 = *(const float4*)(wr);
    float4 w1 = *(const float4*)(wr + 256);
    float4 w2 = *(const float4*)(wr + 512);
    float a = w0.x * x0.x;
    a = fmaf(w0.y, x0.y, a); a = fmaf(w0.z, x0.z, a); a = fmaf(w0.w, x0.w, a);
    a = fmaf(w1.x, x1.x, a); a = fmaf(w1.y, x1.y, a);
    a = fmaf(w1.z, x1.z, a); a = fmaf(w1.w, x1.w, a);
    a = fmaf(w2.x, x2.x, a); a = fmaf(w2.y, x2.y, a);
    a = fmaf(w2.z, x2.z, a); a = fmaf(w2.w, x2.w, a);
#pragma unroll
    for (int off = 32; off; off >>= 1) a += __shfl_xor(a, off);
    if (lane == 0) out1[(size_t)b * C_ + e] = a;
  }
}

// ---- proj (validated R12) --------------------------------------------------
__global__ __launch_bounds__(256) void k_proj2(
    const float* __restrict__ out1, const float* __restrict__ Wproj,
    const float* __restrict__ bproj, float* __restrict__ y) {
  __shared__ __align__(16) float xb[C_];
  const int esl = blockIdx.x, b = blockIdx.y;
  const int tid = threadIdx.x, lane = tid & 63, wv = tid >> 6;

  if (tid < 192) ((float4*)xb)[tid] = ((const float4*)(out1 + (size_t)b * C_))[tid];
  __syncthreads();

  float4 x0 = *(const float4*)(&xb[lane * 4]);
  float4 x1 = *(const float4*)(&xb[256 + lane * 4]);
  float4 x2 = *(const float4*)(&xb[512 + lane * 4]);
#pragma unroll 4
  for (int j = 0; j < 24; ++j) {
    int e = esl * DH_ + wv * 24 + j;
    const float* wr = Wproj + (size_t)e * C_ + lane * 4;
    float4 w0 = *(const float4*)(wr);
    float4 w1 = *(const float4*)(wr + 256);
    float4 w2 = *(const float4*)(wr + 512);
    float a = w0.x * x0.x;
    a = fmaf(w0.y, x0.y, a); a = fmaf(w0.z, x0.z, a); a = fmaf(w0.w, x0.w, a);
    a = fmaf(w1.x, x1.x, a); a = fmaf(w1.y, x1.y, a);
    a = fmaf(w1.z, x1.z, a); a = fmaf(w1.w, x1.w, a);
    a = fmaf(w2.x, x2.x, a); a = fmaf(w2.y, x2.y, a);
    a = fmaf(w2.z, x2.z, a); a = fmaf(w2.w, x2.w, a);
#pragma unroll
    for (int off = 32; off; off >>= 1) a += __shfl_xor(a, off);
    if (lane == 0) y[(size_t)b * C_ + e] = a + bproj[e];
  }
}

extern "C" void kernel_launch(void* const* d_in, const int* in_sizes, int n_in,
                              void* d_out, int out_size, void* d_ws, size_t ws_size,
                              hipStream_t stream) {
  const float* x       = (const float*)d_in[0];
  const float* queries = (const float*)d_in[1];
  const float* Wq      = (const float*)d_in[2];
  const float* Wkv     = (const float*)d_in[3];
  const float* Wproj   = (const float*)d_in[4];
  const float* bproj   = (const float*)d_in[5];
  float* y  = (float*)d_out;
  float* ws = (float*)d_ws;

  float* wqep  = ws;                                   // NDG*H*C = 24576
  float* spart = ws + 24576;                           // B*NCH*H = 4096
  float* part  = ws + 32768;                           // B*NCH*H*C = 3145728
  float* out1  = part + (size_t)B_ * NCH * H_ * C_;    // 24576

  hipLaunchKernelGGL(k_prep,    dim3(H_, NDG),  dim3(256), 0, stream, queries, Wq, Wkv, wqep);
  hipLaunchKernelGGL(k_fused,   dim3(NCH, B_),  dim3(512),
                     3 * TFL * sizeof(float), stream, x, wqep, part, spart);
  hipLaunchKernelGGL(k_combout, dim3(H_, B_),   dim3(256), 0, stream, part, spart, Wkv, out1);
  hipLaunchKernelGGL(k_proj2,   dim3(H_, B_),   dim3(256), 0, stream, out1, Wproj, bproj, y);
}

// Round 20
// 158.845 us; speedup vs baseline: 2.2033x; 2.2033x over previous
//
#include <hip/hip_runtime.h>

// Problem constants
#define B_ 32
#define N_ 4096
#define C_ 768
#define H_ 8
#define DH_ 96
#define TILE 8
#define ROWS 256
#define NT (ROWS / TILE)     // 32 tiles per chunk
#define NCH (N_ / ROWS)      // 16 chunks per batch row
#define TFL (TILE * C_)      // floats per tile buffer (6144)
#define NDG 4                // d-groups in prep (24 d's each)

struct F3 { float x, y, z; };

#define BARL() do { asm volatile("s_waitcnt lgkmcnt(0)" ::: "memory"); \
                    __builtin_amdgcn_s_barrier(); } while (0)

// ---- prep: grid (H, NDG) = 32 blocks. Block (h,dg) owns d in [dg*24,+24):
// phase 1: qh[d] = dot(queries, Wq[h*96+d])   (Wq partitioned exactly)
// phase 2: wqep[dg][h][c] = sum_d qh[d] * Wkv[h*96+d, c]  (partial over dg)
__global__ __launch_bounds__(256) void k_prep(const float* __restrict__ queries,
    const float* __restrict__ Wq, const float* __restrict__ Wkv,
    float* __restrict__ wqep) {
  __shared__ float qh[24];
  const int h = blockIdx.x, dg = blockIdx.y;
  const int tid = threadIdx.x, lane = tid & 63, wv = tid >> 6;
  const int d0 = dg * 24;

  float4 q0 = *(const float4*)(queries + lane * 4);
  float4 q1 = *(const float4*)(queries + 256 + lane * 4);
  float4 q2 = *(const float4*)(queries + 512 + lane * 4);
#pragma unroll
  for (int j = 0; j < 6; ++j) {
    int dl = wv * 6 + j;
    const float* wr = Wq + (size_t)(h * DH_ + d0 + dl) * C_ + lane * 4;
    float4 w0 = *(const float4*)(wr);
    float4 w1 = *(const float4*)(wr + 256);
    float4 w2 = *(const float4*)(wr + 512);
    float a = w0.x * q0.x;
    a = fmaf(w0.y, q0.y, a); a = fmaf(w0.z, q0.z, a); a = fmaf(w0.w, q0.w, a);
    a = fmaf(w1.x, q1.x, a); a = fmaf(w1.y, q1.y, a);
    a = fmaf(w1.z, q1.z, a); a = fmaf(w1.w, q1.w, a);
    a = fmaf(w2.x, q2.x, a); a = fmaf(w2.y, q2.y, a);
    a = fmaf(w2.z, q2.z, a); a = fmaf(w2.w, q2.w, a);
#pragma unroll
    for (int off = 32; off; off >>= 1) a += __shfl_xor(a, off);
    if (lane == 0) qh[dl] = a;
  }
  __syncthreads();

  const int c0 = tid * 3;
  const float* base = Wkv + (size_t)(h * DH_ + d0) * C_ + c0;
  float a0 = 0.f, a1 = 0.f, a2 = 0.f;
#pragma unroll 8
  for (int d = 0; d < 24; ++d) {
    float qd = qh[d];
    const float* p = base + (size_t)d * C_;
    a0 = fmaf(qd, p[0], a0);
    a1 = fmaf(qd, p[1], a1);
    a2 = fmaf(qd, p[2], a2);
  }
  float* o = wqep + ((size_t)dg * H_ + h) * C_ + c0;
  o[0] = a0; o[1] = a1; o[2] = a2;
}

// ---- single-pass fused: pipelined, C-before-wait (R16/R17-validated) ------
// Per iter t:  BARL -> STAGE(t+1) -> C(t-1) -> vmcnt(6) -> A(t)
// Buffers: stage (bi+1)%3, A reads bi, C reads (bi+2)%3. wlds parity-split.
__global__ __attribute__((amdgpu_flat_work_group_size(256, 256),
                          amdgpu_waves_per_eu(2, 2))) void k_fused(
    const float* __restrict__ x, const float* __restrict__ wqep,
    float* __restrict__ part, float* __restrict__ sout) {
  extern __shared__ __align__(16) float xdyn[];       // 3 * TFL (73.7 KB)
  __shared__ __align__(16) float wlds[2][TILE][H_];   // parity-split weights
  __shared__ float sden[4][4];

  const int ch = blockIdx.x, b = blockIdx.y;
  const int tid = threadIdx.x, lane = tid & 63, wid = tid >> 6;
  const int rbase = (wid & 1) * 4;
  const int hbase = (wid >> 1) * 4;
  const int col = lane * 4;
  const float* xc = x + ((size_t)b * N_ + (size_t)ch * ROWS) * C_;

  // wq for this wave's 4 heads: sum the NDG prep partials (one-time cost)
  float4 wqv[4][3];
#pragma unroll
  for (int h = 0; h < 4; ++h)
#pragma unroll
    for (int p = 0; p < 3; ++p) {
      float4 s = *(const float4*)(wqep + (size_t)(hbase + h) * C_ + p * 256 + col);
#pragma unroll
      for (int dg = 1; dg < NDG; ++dg) {
        float4 v = *(const float4*)(wqep + ((size_t)dg * H_ + hbase + h) * C_ + p * 256 + col);
        s.x += v.x; s.y += v.y; s.z += v.z; s.w += v.w;
      }
      wqv[h][p] = s;
    }

  float acc[H_][3];
#pragma unroll
  for (int h = 0; h < H_; ++h) { acc[h][0] = 0.f; acc[h][1] = 0.f; acc[h][2] = 0.f; }
  float sreg = 0.f;

#define STAGE(BI, T) do {                                                      \
    const float* gt_ = xc + (size_t)(T) * TFL;                                 \
    float* bn_ = xdyn + (size_t)(BI) * TFL;                                    \
    _Pragma("unroll")                                                          \
    for (int j = 0; j < 6; ++j) {                                              \
      int k = wid * 6 + j;                                                     \
      __builtin_amdgcn_global_load_lds(                                        \
        (const __attribute__((address_space(1))) void*)(gt_ + k * 256 + lane * 4), \
        (__attribute__((address_space(3))) void*)(bn_ + k * 256),              \
        16, 0, 0);                                                             \
    }                                                                          \
  } while (0)

#define PHASEC(XB, PC) do {                                                    \
    const int c0 = tid * 3;                                                    \
    _Pragma("unroll")                                                          \
    for (int r = 0; r < TILE; ++r) {                                           \
      float4 wA = *(const float4*)(&wlds[PC][r][0]);                           \
      float4 wB = *(const float4*)(&wlds[PC][r][4]);                           \
      F3 xv = *(const F3*)((XB) + (size_t)r * C_ + c0);                        \
      acc[0][0] = fmaf(wA.x, xv.x, acc[0][0]);                                 \
      acc[0][1] = fmaf(wA.x, xv.y, acc[0][1]);                                 \
      acc[0][2] = fmaf(wA.x, xv.z, acc[0][2]);                                 \
      acc[1][0] = fmaf(wA.y, xv.x, acc[1][0]);                                 \
      acc[1][1] = fmaf(wA.y, xv.y, acc[1][1]);                                 \
      acc[1][2] = fmaf(wA.y, xv.z, acc[1][2]);                                 \
      acc[2][0] = fmaf(wA.z, xv.x, acc[2][0]);                                 \
      acc[2][1] = fmaf(wA.z, xv.y, acc[2][1]);                                 \
      acc[2][2] = fmaf(wA.z, xv.z, acc[2][2]);                                 \
      acc[3][0] = fmaf(wA.w, xv.x, acc[3][0]);                                 \
      acc[3][1] = fmaf(wA.w, xv.y, acc[3][1]);                                 \
      acc[3][2] = fmaf(wA.w, xv.z, acc[3][2]);                                 \
      acc[4][0] = fmaf(wB.x, xv.x, acc[4][0]);                                 \
      acc[4][1] = fmaf(wB.x, xv.y, acc[4][1]);                                 \
      acc[4][2] = fmaf(wB.x, xv.z, acc[4][2]);                                 \
      acc[5][0] = fmaf(wB.y, xv.x, acc[5][0]);                                 \
      acc[5][1] = fmaf(wB.y, xv.y, acc[5][1]);                                 \
      acc[5][2] = fmaf(wB.y, xv.z, acc[5][2]);                                 \
      acc[6][0] = fmaf(wB.z, xv.x, acc[6][0]);                                 \
      acc[6][1] = fmaf(wB.z, xv.y, acc[6][1]);                                 \
      acc[6][2] = fmaf(wB.z, xv.z, acc[6][2]);                                 \
      acc[7][0] = fmaf(wB.w, xv.x, acc[7][0]);                                 \
      acc[7][1] = fmaf(wB.w, xv.y, acc[7][1]);                                 \
      acc[7][2] = fmaf(wB.w, xv.z, acc[7][2]);                                 \
    }                                                                          \
  } while (0)

  STAGE(0, 0);   // prologue: tile 0

  int bi = 0;    // buffer of tile t
  for (int t = 0; t < NT; ++t) {
    BARL();   // wlds(t-1) visible; C(t-2) done -> buffer (bi+1)%3 free
    if (t + 1 < NT) { int nb = bi + 1; if (nb >= 3) nb -= 3; STAGE(nb, t + 1); }

    // ---- Phase C(t-1): previous tile (data long resident) ------------------
    if (t > 0) {
      int pb = bi + 2; if (pb >= 3) pb -= 3;
      PHASEC(xdyn + (size_t)pb * TFL, (t & 1) ^ 1);
    }

    // ---- wait for tile t's own 6 loads (t+1's 6 may stay outstanding) ------
    if (t + 1 < NT) { asm volatile("s_waitcnt vmcnt(6)" ::: "memory"); }
    else            { asm volatile("s_waitcnt vmcnt(0)" ::: "memory"); }

    const float* xb = xdyn + (size_t)bi * TFL;
    const int P = t & 1;

    // ---- Phase A(t): 4 rows x 4 heads -> wlds[P] ---------------------------
#pragma unroll
    for (int rr = 0; rr < 4; ++rr) {
      const int r = rbase + rr;
      const float* xr = xb + r * C_ + col;
      float4 xv0 = *(const float4*)(xr);
      float4 xv1 = *(const float4*)(xr + 256);
      float4 xv2 = *(const float4*)(xr + 512);
      float d[4];
#pragma unroll
      for (int h = 0; h < 4; ++h) {
        float a = xv0.x * wqv[h][0].x;
        a = fmaf(xv0.y, wqv[h][0].y, a);
        a = fmaf(xv0.z, wqv[h][0].z, a);
        a = fmaf(xv0.w, wqv[h][0].w, a);
        a = fmaf(xv1.x, wqv[h][1].x, a);
        a = fmaf(xv1.y, wqv[h][1].y, a);
        a = fmaf(xv1.z, wqv[h][1].z, a);
        a = fmaf(xv1.w, wqv[h][1].w, a);
        a = fmaf(xv2.x, wqv[h][2].x, a);
        a = fmaf(xv2.y, wqv[h][2].y, a);
        a = fmaf(xv2.z, wqv[h][2].z, a);
        a = fmaf(xv2.w, wqv[h][2].w, a);
        d[h] = a;
      }
      const int s1 = lane & 1, s2 = lane & 2;
      float A0 = (s1 ? d[1] : d[0]) + __shfl_xor(s1 ? d[0] : d[1], 1);
      float A1 = (s1 ? d[3] : d[2]) + __shfl_xor(s1 ? d[2] : d[3], 1);
      float Q  = (s2 ? A1 : A0) + __shfl_xor(s2 ? A0 : A1, 2);
      Q += __shfl_xor(Q, 4);
      Q += __shfl_xor(Q, 8);
      Q += __shfl_xor(Q, 16);
      Q += __shfl_xor(Q, 32);
      float w = __expf(Q - 20.f);
      if (lane < 4) { wlds[P][r][hbase + lane] = w; sreg += w; }
    }
    ++bi; if (bi >= 3) bi -= 3;
  }

  // final: C(NT-1) — wlds[(NT-1)&1] needs a barrier for visibility
  BARL();
  {
    int pb = bi + 2; if (pb >= 3) pb -= 3;
    PHASEC(xdyn + (size_t)pb * TFL, (NT - 1) & 1);
  }

  // ---- epilogue: chunk partials + denominators ------------------------------
  {
    const int c0 = tid * 3;
    float* pp = part + ((size_t)(b * NCH + ch) * H_) * C_ + c0;
#pragma unroll
    for (int h = 0; h < H_; ++h) {
      F3 o = { acc[h][0], acc[h][1], acc[h][2] };
      *(F3*)(pp + (size_t)h * C_) = o;
    }
    if (lane < 4) sden[wid][lane] = sreg;
    BARL();
    if (tid < H_) {
      int hh = tid >> 2;
      float den = sden[2 * hh][tid & 3] + sden[2 * hh + 1][tid & 3];
      sout[(size_t)(b * NCH + ch) * H_ + tid] = den;
    }
  }
#undef PHASEC
#undef STAGE
}

// ---- combout (validated R12) ----------------------------------------------
__global__ __launch_bounds__(256) void k_combout(
    const float* __restrict__ part, const float* __restrict__ spart,
    const float* __restrict__ Wkv, float* __restrict__ out1) {
  __shared__ __align__(16) float xb[C_];
  const int h = blockIdx.x, b = blockIdx.y;
  const int tid = threadIdx.x, lane = tid & 63, wv = tid >> 6;

  const float* sp = spart + (size_t)b * NCH * H_ + h;
  float den = 0.f;
#pragma unroll
  for (int ch = 0; ch < NCH; ++ch) den += sp[(size_t)ch * H_];
  const float inv = 1.f / den;

  const int c0 = tid * 3;
  const float* pp = part + ((size_t)(b * NCH) * H_ + h) * C_ + c0;
  float a0 = 0.f, a1 = 0.f, a2 = 0.f;
#pragma unroll
  for (int ch = 0; ch < NCH; ++ch) {
    const float* p = pp + (size_t)ch * H_ * C_;
    a0 += p[0]; a1 += p[1]; a2 += p[2];
  }
  xb[c0] = a0 * inv; xb[c0 + 1] = a1 * inv; xb[c0 + 2] = a2 * inv;
  __syncthreads();

  float4 x0 = *(const float4*)(&xb[lane * 4]);
  float4 x1 = *(const float4*)(&xb[256 + lane * 4]);
  float4 x2 = *(const float4*)(&xb[512 + lane * 4]);
#pragma unroll 4
  for (int j = 0; j < 24; ++j) {
    int e = h * DH_ + wv * 24 + j;
    const float* wr = Wkv + (size_t)(C_ + e) * C_ + lane * 4;
    float4 w0 = *(const float4*)(wr);
    float4 w1 = *(const float4*)(wr + 256);
    float4 w2 = *(const float4*)(wr + 512);
    float a = w0.x * x0.x;
    a = fmaf(w0.y, x0.y, a); a = fmaf(w0.z, x0.z, a); a = fmaf(w0.w, x0.w, a);
    a = fmaf(w1.x, x1.x, a); a = fmaf(w1.y, x1.y, a);
    a = fmaf(w1.z, x1.z, a); a = fmaf(w1.w, x1.w, a);
    a = fmaf(w2.x, x2.x, a); a = fmaf(w2.y, x2.y, a);
    a = fmaf(w2.z, x2.z, a); a = fmaf(w2.w, x2.w, a);
#pragma unroll
    for (int off = 32; off; off >>= 1) a += __shfl_xor(a, off);
    if (lane == 0) out1[(size_t)b * C_ + e] = a;
  }
}

// ---- proj (validated R12) --------------------------------------------------
__global__ __launch_bounds__(256) void k_proj2(
    const float* __restrict__ out1, const float* __restrict__ Wproj,
    const float* __restrict__ bproj, float* __restrict__ y) {
  __shared__ __align__(16) float xb[C_];
  const int esl = blockIdx.x, b = blockIdx.y;
  const int tid = threadIdx.x, lane = tid & 63, wv = tid >> 6;

  if (tid < 192) ((float4*)xb)[tid] = ((const float4*)(out1 + (size_t)b * C_))[tid];
  __syncthreads();

  float4 x0 = *(const float4*)(&xb[lane * 4]);
  float4 x1 = *(const float4*)(&xb[256 + lane * 4]);
  float4 x2 = *(const float4*)(&xb[512 + lane * 4]);
#pragma unroll 4
  for (int j = 0; j < 24; ++j) {
    int e = esl * DH_ + wv * 24 + j;
    const float* wr = Wproj + (size_t)e * C_ + lane * 4;
    float4 w0 = *(const float4*)(wr);
    float4 w1 = *(const float4*)(wr + 256);
    float4 w2 = *(const float4*)(wr + 512);
    float a = w0.x * x0.x;
    a = fmaf(w0.y, x0.y, a); a = fmaf(w0.z, x0.z, a); a = fmaf(w0.w, x0.w, a);
    a = fmaf(w1.x, x1.x, a); a = fmaf(w1.y, x1.y, a);
    a = fmaf(w1.z, x1.z, a); a = fmaf(w1.w, x1.w, a);
    a = fmaf(w2.x, x2.x, a); a = fmaf(w2.y, x2.y, a);
    a = fmaf(w2.z, x2.z, a); a = fmaf(w2.w, x2.w, a);
#pragma unroll
    for (int off = 32; off; off >>= 1) a += __shfl_xor(a, off);
    if (lane == 0) y[(size_t)b * C_ + e] = a + bproj[e];
  }
}

extern "C" void kernel_launch(void* const* d_in, const int* in_sizes, int n_in,
                              void* d_out, int out_size, void* d_ws, size_t ws_size,
                              hipStream_t stream) {
  const float* x       = (const float*)d_in[0];
  const float* queries = (const float*)d_in[1];
  const float* Wq      = (const float*)d_in[2];
  const float* Wkv     = (const float*)d_in[3];
  const float* Wproj   = (const float*)d_in[4];
  const float* bproj   = (const float*)d_in[5];
  float* y  = (float*)d_out;
  float* ws = (float*)d_ws;

  float* wqep  = ws;                                   // NDG*H*C = 24576
  float* spart = ws + 24576;                           // B*NCH*H = 4096
  float* part  = ws + 32768;                           // B*NCH*H*C = 3145728
  float* out1  = part + (size_t)B_ * NCH * H_ * C_;    // 24576

  hipLaunchKernelGGL(k_prep,    dim3(H_, NDG),  dim3(256), 0, stream, queries, Wq, Wkv, wqep);
  hipLaunchKernelGGL(k_fused,   dim3(NCH, B_),  dim3(256),
                     3 * TFL * sizeof(float), stream, x, wqep, part, spart);
  hipLaunchKernelGGL(k_combout, dim3(H_, B_),   dim3(256), 0, stream, part, spart, Wkv, out1);
  hipLaunchKernelGGL(k_proj2,   dim3(H_, B_),   dim3(256), 0, stream, out1, Wproj, bproj, y);
}